// Round 9
// baseline (86.016 us; speedup 1.0000x reference)
//
#include <hip/hip_runtime.h>
#include <hip/hip_bf16.h>

typedef float f32x4 __attribute__((ext_vector_type(4)));
typedef short bf16x8 __attribute__((ext_vector_type(8)));
typedef float float4v __attribute__((ext_vector_type(4)));
typedef unsigned short ushort4v __attribute__((ext_vector_type(4)));

#define W2T_OFF (48 * 576)
#define H1_OFF (W2T_OFF + 32 * 1024)   // shorts

__device__ __forceinline__ short f2bf(float f) {
  __bf16 b = (__bf16)f;
  return __builtin_bit_cast(short, b);
}
__device__ __forceinline__ uint pack2(float a, float b) {
  return (uint)(unsigned short)f2bf(a) | ((uint)(unsigned short)f2bf(b) << 16);
}
__device__ __forceinline__ float bf2f(unsigned short u) {
  return __builtin_bit_cast(float, (uint)u << 16);
}
__device__ __forceinline__ float fast_sigmoid(float x) {
  return __builtin_amdgcn_rcpf(1.f + __expf(-x));
}
__device__ __forceinline__ float fast_tanh(float x) {
  float e = __expf(2.f * x);
  return 1.f - 2.f * __builtin_amdgcn_rcpf(e + 1.f);
}
// volatile asm load: compiler CANNOT sink this past its source position.
__device__ __forceinline__ float4v ld16(const float* p) {
  float4v r;
  asm volatile("global_load_dwordx4 %0, %1, off" : "=v"(r) : "v"(p));
  return r;
}

// ---- prep ----
// W1bT region: row n (0..47) of 576 shorts, XOR-swizzled per 16B unit:
//   phys(n,k) = n*576 + (((k>>3) ^ (n&7))<<3) + (k&7)
//   (n<32: W1 col n; n==32: Wr[0:576]; else 0)
// W2T region (linear): W2T[n][k] = W2[k][n]
__global__ __launch_bounds__(256) void prep_weights(
    const float* __restrict__ W1, const float* __restrict__ W2,
    const float* __restrict__ Wr, short* __restrict__ ws)
{
  int i = blockIdx.x * 256 + threadIdx.x;
  if (i < 48 * 576) {
    int n = i / 576;
    int k = i - n * 576;
    float v = 0.f;
    if (n < 32) v = W1[k * 32 + n];
    else if (n == 32) v = Wr[k];
    int phys = n * 576 + ((((k >> 3) ^ (n & 7)) << 3) | (k & 7));
    ws[phys] = f2bf(v);
  } else {
    int j = i - 48 * 576;
    if (j < 32 * 1024) {
      int n = j >> 5;
      int k = j & 31;
      ws[W2T_OFF + j] = f2bf(W2[k * 1024 + n]);
    }
  }
}

// ---- K1: h1 = tanh(X@W1+b1) bf16, rdot = X.Wr[0:576] f32 ----
// 512 thr / 128 rows / grid 512 (2 blocks/CU resident). Weights in LDS (lgkm
// domain) so vmcnt is owned exclusively by the hand-pipelined asm X loads.
// Depth 8 = 16 dwordx4 = 1KB/wave in flight; x16 waves/CU = 16KB/CU.
__global__ __launch_bounds__(512, 4) void fc1_kernel(
    const float* __restrict__ prev_h, const float* __restrict__ action,
    const float* __restrict__ dynamics, const float* __restrict__ b1,
    const short* __restrict__ wsw, short* __restrict__ h1out,
    float* __restrict__ rdot)
{
  __shared__ short wlds[48 * 576];   // 55,296 B

  const int t = threadIdx.x;
  // stage all fc1 weights once: 7 x 8KB rounds, direct-to-LDS
  #pragma unroll
  for (int i = 0; i < 7; ++i) {
    int off = i * 8192 + t * 16;     // bytes
    if (off < 55296) {
      __builtin_amdgcn_global_load_lds(
          (const __attribute__((address_space(1))) void*)((const char*)wsw + off),
          (__attribute__((address_space(3))) void*)((char*)wlds + off), 16, 0, 0);
    }
  }
  __syncthreads();   // drains staging vmcnt; X pipeline starts clean after this

  const int wid = t >> 6, lane = t & 63, lg = lane >> 4, ln = lane & 15;
  const int lnx = ln & 7;
  const int rowA = blockIdx.x * 128 + wid * 16 + ln;
  const int kb = 8 * lg;

  const float* dynp = dynamics + rowA * 256 + kb;
  const float* actp = action   + rowA * 64  + kb;
  const float* hp   = prev_h   + rowA * 256 + kb;

  auto asrc = [&](int j) -> const float* {
    return (j < 8) ? (dynp + 32 * j)
         : (j < 10) ? (actp + 32 * j - 256)
                    : (hp + 32 * j - 320);
  };

  f32x4 acc0 = {0.f,0.f,0.f,0.f};
  f32x4 acc1 = {0.f,0.f,0.f,0.f};
  f32x4 acc2 = {0.f,0.f,0.f,0.f};

  float4v ab[8][2];
  #pragma unroll
  for (int j = 0; j < 8; ++j) {      // prologue: 16 loads in flight
    const float* p = asrc(j);
    ab[j][0] = ld16(p);
    ab[j][1] = ld16(p + 4);
  }

#define FC1_STEP(J, S, IMM)                                                  \
  {                                                                          \
    asm volatile("s_waitcnt vmcnt(" #IMM ")");                               \
    __builtin_amdgcn_sched_barrier(0);                                       \
    float4v v0 = ab[S][0], v1 = ab[S][1];                                    \
    bf16x8 a;                                                                \
    a[0]=f2bf(v0.x); a[1]=f2bf(v0.y); a[2]=f2bf(v0.z); a[3]=f2bf(v0.w);      \
    a[4]=f2bf(v1.x); a[5]=f2bf(v1.y); a[6]=f2bf(v1.z); a[7]=f2bf(v1.w);      \
    const int uo = ((4 * (J) + lg) ^ lnx) << 3;                              \
    bf16x8 bA = *(const bf16x8*)&wlds[ln * 576 + uo];                        \
    bf16x8 bB = *(const bf16x8*)&wlds[(ln + 16) * 576 + uo];                 \
    bf16x8 bC = *(const bf16x8*)&wlds[(ln + 32) * 576 + uo];                 \
    acc0 = __builtin_amdgcn_mfma_f32_16x16x32_bf16(bA, a, acc0, 0, 0, 0);    \
    acc1 = __builtin_amdgcn_mfma_f32_16x16x32_bf16(bB, a, acc1, 0, 0, 0);    \
    acc2 = __builtin_amdgcn_mfma_f32_16x16x32_bf16(bC, a, acc2, 0, 0, 0);    \
    if ((J) + 8 < 18) {                                                      \
      const float* np = asrc((J) + 8);                                       \
      ab[S][0] = ld16(np);                                                   \
      ab[S][1] = ld16(np + 4);                                               \
    }                                                                        \
  }

  FC1_STEP(0,0,14)  FC1_STEP(1,1,14)  FC1_STEP(2,2,14)  FC1_STEP(3,3,14)
  FC1_STEP(4,4,14)  FC1_STEP(5,5,14)  FC1_STEP(6,6,14)  FC1_STEP(7,7,14)
  FC1_STEP(8,0,14)  FC1_STEP(9,1,14)  FC1_STEP(10,2,14) FC1_STEP(11,3,12)
  FC1_STEP(12,4,10) FC1_STEP(13,5,8)  FC1_STEP(14,6,6)  FC1_STEP(15,7,4)
  FC1_STEP(16,0,2)  FC1_STEP(17,1,0)
#undef FC1_STEP

  // epilogue: tanh + bias, pack bf16, store h1 row + rdot
  float4v b1lo = *(const float4v*)&b1[4 * lg];
  float4v b1hi = *(const float4v*)&b1[16 + 4 * lg];
  uint2 wlo, whi;
  wlo.x = pack2(fast_tanh(acc0[0] + b1lo.x), fast_tanh(acc0[1] + b1lo.y));
  wlo.y = pack2(fast_tanh(acc0[2] + b1lo.z), fast_tanh(acc0[3] + b1lo.w));
  whi.x = pack2(fast_tanh(acc1[0] + b1hi.x), fast_tanh(acc1[1] + b1hi.y));
  whi.y = pack2(fast_tanh(acc1[2] + b1hi.z), fast_tanh(acc1[3] + b1hi.w));
  *(uint2*)&h1out[rowA * 32 + 4 * lg]      = wlo;
  *(uint2*)&h1out[rowA * 32 + 16 + 4 * lg] = whi;
  if (lg == 0) rdot[rowA] = acc2[0];
}

// ---- K2: gates = h1@W2+b2, LSTM update, reward ----
// 256 thr / 32 rows / grid 2048. prev_c staged in LDS as BF16 (16KB/block ->
// 8 blocks/CU = 100% occupancy at 64-VGPR cap; accuracy budget: +|pc|*2^-9
// ~= 0.011 abs, threshold 0.056). XOR-swizzled 8B units: phys_u = u^(row&7)
// -> 2-way banks on both write and the per-tile ds_read.
__global__ __launch_bounds__(256, 8) void fc2_kernel(
    const float* __restrict__ prev_c, const float* __restrict__ b2,
    const float* __restrict__ Wr, const float* __restrict__ br,
    const short* __restrict__ wsw, const short* __restrict__ h1in,
    const float* __restrict__ rdot,
    float* __restrict__ out_h, float* __restrict__ out_c, float* __restrict__ out_r)
{
  __shared__ unsigned short pc_lds[32 * 256];   // 16 KB (32 rows x 64 units x 4 bf16)
  __shared__ float rlds[2][16];

  const int t = threadIdx.x;
  const int wid = t >> 6, lane = t & 63, lg = lane >> 4, ln = lane & 15;
  const int p = wid >> 1, ks = wid & 1;
  const int r0 = blockIdx.x * 32;
  const int rowA = r0 + p * 16 + ln;

  // stage prev_c rows r0..r0+31 as bf16, swizzled
  #pragma unroll
  for (int i = 0; i < 8; ++i) {
    int v = i * 256 + t;            // 8B unit index 0..2047
    int row = v >> 6, u = v & 63;
    float4v pv = *(const float4v*)(prev_c + (size_t)(r0 + row) * 256 + u * 4);
    uint2 w;
    w.x = pack2(pv.x, pv.y);
    w.y = pack2(pv.z, pv.w);
    *(uint2*)&pc_lds[(row * 64 + (u ^ (row & 7))) * 4] = w;
  }
  // h1 fragment (completes by the barrier)
  bf16x8 af2 = *(const bf16x8*)&h1in[rowA * 32 + 8 * lg];
  __syncthreads();

  float racc = 0.f;
  const float br0 = br[0];
  const short* w2t = wsw + W2T_OFF;
  const size_t orow = (size_t)rowA * 256;
  const int lrow = (p * 16 + ln) * 64;   // this lane's LDS row base (8B units)
  const int lnx = ln & 7;

  auto fc2_tile = [&](int nt, float4v& nh, float4v& nc2) {
    const int c4 = nt * 16 + 4 * lg;
    const short* aw = w2t + (nt * 16 + ln) * 32 + 8 * lg;
    bf16x8 wi = *(const bf16x8*)(aw);
    bf16x8 wf = *(const bf16x8*)(aw + 256 * 32);
    bf16x8 wc = *(const bf16x8*)(aw + 512 * 32);
    bf16x8 wo = *(const bf16x8*)(aw + 768 * 32);
    f32x4 gi = {0.f,0.f,0.f,0.f}, gf = {0.f,0.f,0.f,0.f};
    f32x4 gc = {0.f,0.f,0.f,0.f}, go = {0.f,0.f,0.f,0.f};
    gi = __builtin_amdgcn_mfma_f32_16x16x32_bf16(wi, af2, gi, 0, 0, 0);
    gf = __builtin_amdgcn_mfma_f32_16x16x32_bf16(wf, af2, gf, 0, 0, 0);
    gc = __builtin_amdgcn_mfma_f32_16x16x32_bf16(wc, af2, gc, 0, 0, 0);
    go = __builtin_amdgcn_mfma_f32_16x16x32_bf16(wo, af2, go, 0, 0, 0);
    ushort4v pcb = *(const ushort4v*)&pc_lds[(lrow + ((nt * 4 + lg) ^ lnx)) * 4];
    float4v b2i = *(const float4v*)&b2[c4];
    float4v b2f = *(const float4v*)&b2[256 + c4];
    float4v b2c = *(const float4v*)&b2[512 + c4];
    float4v b2o = *(const float4v*)&b2[768 + c4];
    float4v wrv = *(const float4v*)&Wr[576 + c4];
    #pragma unroll
    for (int r = 0; r < 4; ++r) {
      float iv  = fast_sigmoid(gi[r] + b2i[r]);
      float fv  = fast_sigmoid(gf[r] + b2f[r]);
      float cv  = fast_tanh(gc[r] + b2c[r]);
      float ov  = fast_sigmoid(go[r] + b2o[r]);
      float ncv = fv * bf2f(pcb[r]) + iv * cv;
      float nhv = ov * fast_tanh(ncv);
      nh[r]  = nhv;
      nc2[r] = ncv;
      racc += nhv * wrv[r];
    }
  };

  #pragma unroll
  for (int qq = 0; qq < 4; ++qq) {
    const int nt0 = ks * 8 + 2 * qq;
    float4v nh0, nc0, nh1, nc1;
    fc2_tile(nt0,     nh0, nc0);
    fc2_tile(nt0 + 1, nh1, nc1);
    const size_t b0 = orow + nt0 * 16 + 4 * lg;
    __builtin_nontemporal_store(nh0, (float4v*)(out_h + b0));
    __builtin_nontemporal_store(nh1, (float4v*)(out_h + b0 + 16));
    __builtin_nontemporal_store(nc0, (float4v*)(out_c + b0));
    __builtin_nontemporal_store(nc1, (float4v*)(out_c + b0 + 16));
  }

  // reward: fold lg groups, then combine the wave pair via LDS
  racc += __shfl_xor(racc, 16, 64);
  racc += __shfl_xor(racc, 32, 64);
  if (ks == 1 && lane < 16) rlds[p][lane] = racc;
  asm volatile("s_waitcnt lgkmcnt(0)" ::: "memory");
  __builtin_amdgcn_s_barrier();
  __builtin_amdgcn_sched_barrier(0);
  if (ks == 0 && lg == 0) {
    float s = rdot[rowA] + racc + rlds[p][ln] + br0;
    __builtin_nontemporal_store(fast_tanh(s), &out_r[rowA]);
  }
}

extern "C" void kernel_launch(void* const* d_in, const int* in_sizes, int n_in,
                              void* d_out, int out_size, void* d_ws, size_t ws_size,
                              hipStream_t stream) {
  const float* prev_h   = (const float*)d_in[0];
  const float* prev_c   = (const float*)d_in[1];
  const float* action   = (const float*)d_in[2];
  const float* dynamics = (const float*)d_in[3];
  const float* W1 = (const float*)d_in[4];
  const float* b1 = (const float*)d_in[5];
  const float* W2 = (const float*)d_in[6];
  const float* b2 = (const float*)d_in[7];
  const float* Wr = (const float*)d_in[8];
  const float* br = (const float*)d_in[9];

  short* wsw   = (short*)d_ws;
  short* h1buf = wsw + H1_OFF;                          // [B,32] bf16 = 4 MB
  float* rdot  = (float*)(h1buf + (size_t)65536 * 32);  // [B] f32 = 256 KB

  float* out_h = (float*)d_out;
  float* out_c = out_h + (size_t)65536 * 256;
  float* out_r = out_c + (size_t)65536 * 256;

  prep_weights<<<236, 256, 0, stream>>>(W1, W2, Wr, wsw);
  fc1_kernel<<<512, 512, 0, stream>>>(prev_h, action, dynamics, b1, wsw, h1buf, rdot);
  fc2_kernel<<<2048, 256, 0, stream>>>(prev_c, b2, Wr, br, wsw, h1buf, rdot,
                                       out_h, out_c, out_r);
}

// Round 10
// 78.975 us; speedup vs baseline: 1.0892x; 1.0892x over previous
//
#include <hip/hip_runtime.h>
#include <hip/hip_bf16.h>

typedef float f32x4 __attribute__((ext_vector_type(4)));
typedef short bf16x8 __attribute__((ext_vector_type(8)));
typedef float float4v __attribute__((ext_vector_type(4)));

#define W2T_OFF (48 * 576)
#define H1_OFF (W2T_OFF + 32 * 1024)   // shorts

__device__ __forceinline__ short f2bf(float f) {
  __bf16 b = (__bf16)f;
  return __builtin_bit_cast(short, b);
}
__device__ __forceinline__ uint pack2(float a, float b) {
  return (uint)(unsigned short)f2bf(a) | ((uint)(unsigned short)f2bf(b) << 16);
}
__device__ __forceinline__ float fast_sigmoid(float x) {
  return __builtin_amdgcn_rcpf(1.f + __expf(-x));
}
__device__ __forceinline__ float fast_tanh(float x) {
  float e = __expf(2.f * x);
  return 1.f - 2.f * __builtin_amdgcn_rcpf(e + 1.f);
}
// volatile asm load: compiler CANNOT sink this past its source position.
__device__ __forceinline__ float4v ld16(const float* p) {
  float4v r;
  asm volatile("global_load_dwordx4 %0, %1, off" : "=v"(r) : "v"(p));
  return r;
}

// ---- prep ----
// W1bT region: row n (0..47) of 576 shorts, XOR-swizzled per 16B unit:
//   phys(n,k) = n*576 + (((k>>3) ^ (n&7))<<3) + (k&7)
//   (n<32: W1 col n; n==32: Wr[0:576]; else 0)
// W2T region (linear): W2T[n][k] = W2[k][n]
__global__ __launch_bounds__(256) void prep_weights(
    const float* __restrict__ W1, const float* __restrict__ W2,
    const float* __restrict__ Wr, short* __restrict__ ws)
{
  int i = blockIdx.x * 256 + threadIdx.x;
  if (i < 48 * 576) {
    int n = i / 576;
    int k = i - n * 576;
    float v = 0.f;
    if (n < 32) v = W1[k * 32 + n];
    else if (n == 32) v = Wr[k];
    int phys = n * 576 + ((((k >> 3) ^ (n & 7)) << 3) | (k & 7));
    ws[phys] = f2bf(v);
  } else {
    int j = i - 48 * 576;
    if (j < 32 * 1024) {
      int n = j >> 5;
      int k = j & 31;
      ws[W2T_OFF + j] = f2bf(W2[k * 1024 + n]);
    }
  }
}

// ---- K1: h1 = tanh(X@W1+b1) bf16, rdot = X.Wr[0:576] f32 ----
// EXACT r8 configuration (known-good, part of the 77.8us wall).
// 512 thr / 128 rows / grid 512. Weights in LDS (lgkm domain) so vmcnt is
// owned exclusively by the hand-pipelined asm X loads (depth 6 = 12 dwordx4).
__global__ __launch_bounds__(512, 4) void fc1_kernel(
    const float* __restrict__ prev_h, const float* __restrict__ action,
    const float* __restrict__ dynamics, const float* __restrict__ b1,
    const short* __restrict__ wsw, short* __restrict__ h1out,
    float* __restrict__ rdot)
{
  __shared__ short wlds[48 * 576];   // 55,296 B

  const int t = threadIdx.x;
  #pragma unroll
  for (int i = 0; i < 7; ++i) {
    int off = i * 8192 + t * 16;     // bytes
    if (off < 55296) {
      __builtin_amdgcn_global_load_lds(
          (const __attribute__((address_space(1))) void*)((const char*)wsw + off),
          (__attribute__((address_space(3))) void*)((char*)wlds + off), 16, 0, 0);
    }
  }
  __syncthreads();   // drains staging vmcnt; X pipeline starts clean after this

  const int wid = t >> 6, lane = t & 63, lg = lane >> 4, ln = lane & 15;
  const int lnx = ln & 7;
  const int rowA = blockIdx.x * 128 + wid * 16 + ln;
  const int kb = 8 * lg;

  const float* dynp = dynamics + rowA * 256 + kb;
  const float* actp = action   + rowA * 64  + kb;
  const float* hp   = prev_h   + rowA * 256 + kb;

  auto asrc = [&](int j) -> const float* {
    return (j < 8) ? (dynp + 32 * j)
         : (j < 10) ? (actp + 32 * j - 256)
                    : (hp + 32 * j - 320);
  };

  f32x4 acc0 = {0.f,0.f,0.f,0.f};
  f32x4 acc1 = {0.f,0.f,0.f,0.f};
  f32x4 acc2 = {0.f,0.f,0.f,0.f};

  float4v ab[6][2];
  #pragma unroll
  for (int j = 0; j < 6; ++j) {      // prologue: 12 loads in flight
    const float* p = asrc(j);
    ab[j][0] = ld16(p);
    ab[j][1] = ld16(p + 4);
  }

#define FC1_STEP(J, S, IMM)                                                  \
  {                                                                          \
    asm volatile("s_waitcnt vmcnt(" #IMM ")");                               \
    __builtin_amdgcn_sched_barrier(0);                                       \
    float4v v0 = ab[S][0], v1 = ab[S][1];                                    \
    bf16x8 a;                                                                \
    a[0]=f2bf(v0.x); a[1]=f2bf(v0.y); a[2]=f2bf(v0.z); a[3]=f2bf(v0.w);      \
    a[4]=f2bf(v1.x); a[5]=f2bf(v1.y); a[6]=f2bf(v1.z); a[7]=f2bf(v1.w);      \
    const int uo = ((4 * (J) + lg) ^ lnx) << 3;                              \
    bf16x8 bA = *(const bf16x8*)&wlds[ln * 576 + uo];                        \
    bf16x8 bB = *(const bf16x8*)&wlds[(ln + 16) * 576 + uo];                 \
    bf16x8 bC = *(const bf16x8*)&wlds[(ln + 32) * 576 + uo];                 \
    acc0 = __builtin_amdgcn_mfma_f32_16x16x32_bf16(bA, a, acc0, 0, 0, 0);    \
    acc1 = __builtin_amdgcn_mfma_f32_16x16x32_bf16(bB, a, acc1, 0, 0, 0);    \
    acc2 = __builtin_amdgcn_mfma_f32_16x16x32_bf16(bC, a, acc2, 0, 0, 0);    \
    if ((J) + 6 < 18) {                                                      \
      const float* np = asrc((J) + 6);                                       \
      ab[S][0] = ld16(np);                                                   \
      ab[S][1] = ld16(np + 4);                                               \
    }                                                                        \
  }

  FC1_STEP(0,0,10)  FC1_STEP(1,1,10)  FC1_STEP(2,2,10)  FC1_STEP(3,3,10)
  FC1_STEP(4,4,10)  FC1_STEP(5,5,10)  FC1_STEP(6,0,10)  FC1_STEP(7,1,10)
  FC1_STEP(8,2,10)  FC1_STEP(9,3,10)  FC1_STEP(10,4,10) FC1_STEP(11,5,10)
  FC1_STEP(12,0,10) FC1_STEP(13,1,8)  FC1_STEP(14,2,6)  FC1_STEP(15,3,4)
  FC1_STEP(16,4,2)  FC1_STEP(17,5,0)
#undef FC1_STEP

  float4v b1lo = *(const float4v*)&b1[4 * lg];
  float4v b1hi = *(const float4v*)&b1[16 + 4 * lg];
  uint2 wlo, whi;
  wlo.x = pack2(fast_tanh(acc0[0] + b1lo.x), fast_tanh(acc0[1] + b1lo.y));
  wlo.y = pack2(fast_tanh(acc0[2] + b1lo.z), fast_tanh(acc0[3] + b1lo.w));
  whi.x = pack2(fast_tanh(acc1[0] + b1hi.x), fast_tanh(acc1[1] + b1hi.y));
  whi.y = pack2(fast_tanh(acc1[2] + b1hi.z), fast_tanh(acc1[3] + b1hi.w));
  *(uint2*)&h1out[rowA * 32 + 4 * lg]      = wlo;
  *(uint2*)&h1out[rowA * 32 + 16 + 4 * lg] = whi;
  if (lg == 0) rdot[rowA] = acc2[0];
}

// ---- K2: gates = h1@W2+b2, LSTM update, reward ----
// CHANGE vs r8: 16 rows/block (grid 4096), wave ks owns col-quarter (4 tiles).
// pc_lds halves to 16KB fp32 -> 8 blocks/CU = 32 waves/CU = 100% occupancy at
// the (256,8) 64-VGPR cap (demand ~40: pc lives in LDS, no register arrays).
// Staging mechanism identical to r8: global_load_lds, linear LDS dest,
// XOR pre-swizzled global source (16B units: u ^ (row&7)).
__global__ __launch_bounds__(256, 8) void fc2_kernel(
    const float* __restrict__ prev_c, const float* __restrict__ b2,
    const float* __restrict__ Wr, const float* __restrict__ br,
    const short* __restrict__ wsw, const short* __restrict__ h1in,
    const float* __restrict__ rdot,
    float* __restrict__ out_h, float* __restrict__ out_c, float* __restrict__ out_r)
{
  __shared__ float pc_lds[16 * 256];   // 16 KB
  __shared__ float rlds[4][16];

  const int t = threadIdx.x;
  const int ks = t >> 6, lane = t & 63, lg = lane >> 4, ln = lane & 15;
  const int r0 = blockIdx.x * 16;
  const int rowA = r0 + ln;            // all 4 waves share these 16 rows

  // stage prev_c rows r0..r0+15: linear LDS dest, pre-swizzled global source
  {
    const float* src = prev_c + (size_t)r0 * 256;
    #pragma unroll
    for (int i = 0; i < 4; ++i) {
      int u = i * 256 + t;                             // 16B unit 0..1023
      int g = (u & ~63) | ((u & 63) ^ ((u >> 6) & 7)); // swizzled source unit
      __builtin_amdgcn_global_load_lds(
          (const __attribute__((address_space(1))) void*)(src + g * 4),
          (__attribute__((address_space(3))) void*)&pc_lds[u * 4], 16, 0, 0);
    }
  }
  // h1 fragment (drained by the same barrier)
  bf16x8 af2 = *(const bf16x8*)&h1in[rowA * 32 + 8 * lg];
  __syncthreads();

  float racc = 0.f;
  const float br0 = br[0];
  const short* w2t = wsw + W2T_OFF;
  const size_t orow = (size_t)rowA * 256;
  const int lrow = ln * 64;            // this lane's LDS row base (16B units)
  const int lnx = ln & 7;

  auto fc2_tile = [&](int nt, float4v& nh, float4v& nc2) {
    const int c4 = nt * 16 + 4 * lg;
    const short* aw = w2t + (nt * 16 + ln) * 32 + 8 * lg;
    bf16x8 wi = *(const bf16x8*)(aw);
    bf16x8 wf = *(const bf16x8*)(aw + 256 * 32);
    bf16x8 wc = *(const bf16x8*)(aw + 512 * 32);
    bf16x8 wo = *(const bf16x8*)(aw + 768 * 32);
    f32x4 gi = {0.f,0.f,0.f,0.f}, gf = {0.f,0.f,0.f,0.f};
    f32x4 gc = {0.f,0.f,0.f,0.f}, go = {0.f,0.f,0.f,0.f};
    gi = __builtin_amdgcn_mfma_f32_16x16x32_bf16(wi, af2, gi, 0, 0, 0);
    gf = __builtin_amdgcn_mfma_f32_16x16x32_bf16(wf, af2, gf, 0, 0, 0);
    gc = __builtin_amdgcn_mfma_f32_16x16x32_bf16(wc, af2, gc, 0, 0, 0);
    go = __builtin_amdgcn_mfma_f32_16x16x32_bf16(wo, af2, go, 0, 0, 0);
    float4v pc = *(const float4v*)&pc_lds[(lrow + ((nt * 4 + lg) ^ lnx)) * 4];
    float4v b2i = *(const float4v*)&b2[c4];
    float4v b2f = *(const float4v*)&b2[256 + c4];
    float4v b2c = *(const float4v*)&b2[512 + c4];
    float4v b2o = *(const float4v*)&b2[768 + c4];
    float4v wrv = *(const float4v*)&Wr[576 + c4];
    #pragma unroll
    for (int r = 0; r < 4; ++r) {
      float iv  = fast_sigmoid(gi[r] + b2i[r]);
      float fv  = fast_sigmoid(gf[r] + b2f[r]);
      float cv  = fast_tanh(gc[r] + b2c[r]);
      float ov  = fast_sigmoid(go[r] + b2o[r]);
      float ncv = fv * pc[r] + iv * cv;
      float nhv = ov * fast_tanh(ncv);
      nh[r]  = nhv;
      nc2[r] = ncv;
      racc += nhv * wrv[r];
    }
  };

  // 2 pairs of adjacent tiles -> adjacent-64B NT stores merge into 128B lines
  #pragma unroll
  for (int qq = 0; qq < 2; ++qq) {
    const int nt0 = ks * 4 + 2 * qq;
    float4v nh0, nc0, nh1, nc1;
    fc2_tile(nt0,     nh0, nc0);
    fc2_tile(nt0 + 1, nh1, nc1);
    const size_t b0 = orow + nt0 * 16 + 4 * lg;
    __builtin_nontemporal_store(nh0, (float4v*)(out_h + b0));
    __builtin_nontemporal_store(nh1, (float4v*)(out_h + b0 + 16));
    __builtin_nontemporal_store(nc0, (float4v*)(out_c + b0));
    __builtin_nontemporal_store(nc1, (float4v*)(out_c + b0 + 16));
  }

  // reward: fold lg groups (lanes ln,ln+16,ln+32,ln+48 all end with row ln's
  // quarter-sum), then combine the 4 waves via LDS (no vmcnt drain).
  racc += __shfl_xor(racc, 16, 64);
  racc += __shfl_xor(racc, 32, 64);
  if (ks > 0 && lane < 16) rlds[ks][lane] = racc;
  asm volatile("s_waitcnt lgkmcnt(0)" ::: "memory");
  __builtin_amdgcn_s_barrier();
  __builtin_amdgcn_sched_barrier(0);
  if (ks == 0 && lg == 0) {
    float s = rdot[rowA] + racc + rlds[1][ln] + rlds[2][ln] + rlds[3][ln] + br0;
    __builtin_nontemporal_store(fast_tanh(s), &out_r[rowA]);
  }
}

extern "C" void kernel_launch(void* const* d_in, const int* in_sizes, int n_in,
                              void* d_out, int out_size, void* d_ws, size_t ws_size,
                              hipStream_t stream) {
  const float* prev_h   = (const float*)d_in[0];
  const float* prev_c   = (const float*)d_in[1];
  const float* action   = (const float*)d_in[2];
  const float* dynamics = (const float*)d_in[3];
  const float* W1 = (const float*)d_in[4];
  const float* b1 = (const float*)d_in[5];
  const float* W2 = (const float*)d_in[6];
  const float* b2 = (const float*)d_in[7];
  const float* Wr = (const float*)d_in[8];
  const float* br = (const float*)d_in[9];

  short* wsw   = (short*)d_ws;
  short* h1buf = wsw + H1_OFF;                          // [B,32] bf16 = 4 MB
  float* rdot  = (float*)(h1buf + (size_t)65536 * 32);  // [B] f32 = 256 KB

  float* out_h = (float*)d_out;
  float* out_c = out_h + (size_t)65536 * 256;
  float* out_r = out_c + (size_t)65536 * 256;

  prep_weights<<<236, 256, 0, stream>>>(W1, W2, Wr, wsw);
  fc1_kernel<<<512, 512, 0, stream>>>(prev_h, action, dynamics, b1, wsw, h1buf, rdot);
  fc2_kernel<<<4096, 256, 0, stream>>>(prev_c, b2, Wr, br, wsw, h1buf, rdot,
                                       out_h, out_c, out_r);
}

// Round 12
// 69.412 us; speedup vs baseline: 1.2392x; 1.1378x over previous
//
#include <hip/hip_runtime.h>
#include <hip/hip_bf16.h>

typedef float f32x4 __attribute__((ext_vector_type(4)));
typedef short bf16x8 __attribute__((ext_vector_type(8)));
typedef float float4v __attribute__((ext_vector_type(4)));

#define W2T_OFF (48 * 576)
#define BIAS_OFF 60416        // shorts; byte offset 120832 (16B-aligned)
#define BIAS_FLOATS 1328      // b2[1024] | Wr576..831[256] | b1[32] | br[1] | pad[15]

__device__ __forceinline__ short f2bf(float f) {
  __bf16 b = (__bf16)f;
  return __builtin_bit_cast(short, b);
}
__device__ __forceinline__ uint pack2(float a, float b) {
  return (uint)(unsigned short)f2bf(a) | ((uint)(unsigned short)f2bf(b) << 16);
}
__device__ __forceinline__ float fast_sigmoid(float x) {
  return __builtin_amdgcn_rcpf(1.f + __expf(-x));
}
__device__ __forceinline__ float fast_tanh(float x) {
  float e = __expf(2.f * x);
  return 1.f - 2.f * __builtin_amdgcn_rcpf(e + 1.f);
}
// volatile asm loads: compiler cannot sink/hoist these.
__device__ __forceinline__ float4v ld16(const float* p) {
  float4v r;
  asm volatile("global_load_dwordx4 %0, %1, off" : "=v"(r) : "v"(p));
  return r;
}
__device__ __forceinline__ bf16x8 ld16w(const short* p) {
  bf16x8 r;
  asm volatile("global_load_dwordx4 %0, %1, off" : "=v"(r) : "v"(p));
  return r;
}

// ---- prep: weights (bf16, swizzled) + bias block (f32) in d_ws ----
// [0,27648)       shorts: W1bT row n, XOR-swizzled 16B units (n<32: W1 col n; n==32: Wr[0:576]; else 0)
// [27648,60416)   shorts: W2T[n][k] = W2[k][n]
// [60416,63072)   = f32 bias block: b2 | Wr[576:832] | b1 | br | pad
__global__ __launch_bounds__(256) void prep_weights(
    const float* __restrict__ W1, const float* __restrict__ W2,
    const float* __restrict__ Wr, const float* __restrict__ b1,
    const float* __restrict__ b2, const float* __restrict__ br,
    short* __restrict__ ws)
{
  int i = blockIdx.x * 256 + threadIdx.x;
  if (i < 48 * 576) {
    int n = i / 576;
    int k = i - n * 576;
    float v = 0.f;
    if (n < 32) v = W1[k * 32 + n];
    else if (n == 32) v = Wr[k];
    int phys = n * 576 + ((((k >> 3) ^ (n & 7)) << 3) | (k & 7));
    ws[phys] = f2bf(v);
  } else if (i < BIAS_OFF) {
    int j = i - 48 * 576;
    int n = j >> 5, k = j & 31;
    ws[W2T_OFF + j] = f2bf(W2[k * 1024 + n]);
  } else {
    int i2 = i - BIAS_OFF;
    if (i2 < BIAS_FLOATS) {
      float v = 0.f;
      if (i2 < 1024) v = b2[i2];
      else if (i2 < 1280) v = Wr[576 + (i2 - 1024)];
      else if (i2 < 1312) v = b1[i2 - 1280];
      else if (i2 == 1312) v = br[0];
      ((float*)(ws + BIAS_OFF))[i2] = v;
    }
  }
}

// ---- fused: fc1 (r8 body) -> wave-local h1 -> fc2 (pc depth-3, W ping-pong-2) ----
// 512 thr / 8 waves / 128 rows / grid 512. LDS 70,848 B -> 2 blocks/CU.
// vmcnt literals count LOADS ONLY (robust to store sinking); next-tile loads
// issued AFTER the stores so the interleaved case is exact. NO load is ever
// issued whose result is dead (r11 bug: dead asm outputs -> phys-reg reuse ->
// in-flight load clobbers live data).
__global__ __launch_bounds__(512) void fclstm_fused(
    const float* __restrict__ prev_h, const float* __restrict__ prev_c,
    const float* __restrict__ action, const float* __restrict__ dynamics,
    const short* __restrict__ wsw,
    float* __restrict__ out_h, float* __restrict__ out_c, float* __restrict__ out_r)
{
  __shared__ short wlds[48 * 576];   // 55,296 B : fc1 weights (swizzled)
  __shared__ short h1T[128 * 40];    // 10,240 B : h1 transpose (wave-local rows)
  __shared__ float blds[BIAS_FLOATS]; // 5,312 B : bias block

  const int t = threadIdx.x;

  // ---- stage weights + biases direct-to-LDS (drained by the barrier) ----
  #pragma unroll
  for (int i = 0; i < 7; ++i) {
    int off = i * 8192 + t * 16;     // bytes
    if (off < 55296) {
      __builtin_amdgcn_global_load_lds(
          (const __attribute__((address_space(1))) void*)((const char*)wsw + off),
          (__attribute__((address_space(3))) void*)((char*)wlds + off), 16, 0, 0);
    }
  }
  {
    const float* bsrc = (const float*)(wsw + BIAS_OFF);
    if (t < BIAS_FLOATS / 4) {       // 332 16B units, linear lane mapping
      __builtin_amdgcn_global_load_lds(
          (const __attribute__((address_space(1))) void*)(bsrc + t * 4),
          (__attribute__((address_space(3))) void*)&blds[t * 4], 16, 0, 0);
    }
  }
  __syncthreads();   // drains staging vmcnt; pipelines start clean

  const int wid = t >> 6, lane = t & 63, lg = lane >> 4, ln = lane & 15;
  const int lnx = ln & 7;
  const int rowL = wid * 16 + ln;
  const int rowA = blockIdx.x * 128 + rowL;
  const int kb = 8 * lg;

  const float* dynp = dynamics + rowA * 256 + kb;
  const float* actp = action   + rowA * 64  + kb;
  const float* hp   = prev_h   + rowA * 256 + kb;

  auto asrc = [&](int j) -> const float* {
    return (j < 8) ? (dynp + 32 * j)
         : (j < 10) ? (actp + 32 * j - 256)
                    : (hp + 32 * j - 320);
  };

  // ---- fc1: depth-6 volatile X pipeline (r8 literals; no stores in stream) ----
  f32x4 acc0 = {0.f,0.f,0.f,0.f};
  f32x4 acc1 = {0.f,0.f,0.f,0.f};
  f32x4 acc2 = {0.f,0.f,0.f,0.f};   // col 32 = x . Wr[0:576] (lg==0, reg 0)

  float4v ab[6][2];
  #pragma unroll
  for (int j = 0; j < 6; ++j) {
    const float* p = asrc(j);
    ab[j][0] = ld16(p);
    ab[j][1] = ld16(p + 4);
  }

#define FC1_STEP(J, S, IMM)                                                  \
  {                                                                          \
    asm volatile("s_waitcnt vmcnt(" #IMM ")");                               \
    __builtin_amdgcn_sched_barrier(0);                                       \
    float4v v0 = ab[S][0], v1 = ab[S][1];                                    \
    bf16x8 a;                                                                \
    a[0]=f2bf(v0.x); a[1]=f2bf(v0.y); a[2]=f2bf(v0.z); a[3]=f2bf(v0.w);      \
    a[4]=f2bf(v1.x); a[5]=f2bf(v1.y); a[6]=f2bf(v1.z); a[7]=f2bf(v1.w);      \
    const int uo = ((4 * (J) + lg) ^ lnx) << 3;                              \
    bf16x8 bA = *(const bf16x8*)&wlds[ln * 576 + uo];                        \
    bf16x8 bB = *(const bf16x8*)&wlds[(ln + 16) * 576 + uo];                 \
    bf16x8 bC = *(const bf16x8*)&wlds[(ln + 32) * 576 + uo];                 \
    acc0 = __builtin_amdgcn_mfma_f32_16x16x32_bf16(bA, a, acc0, 0, 0, 0);    \
    acc1 = __builtin_amdgcn_mfma_f32_16x16x32_bf16(bB, a, acc1, 0, 0, 0);    \
    acc2 = __builtin_amdgcn_mfma_f32_16x16x32_bf16(bC, a, acc2, 0, 0, 0);    \
    if ((J) + 6 < 18) {                                                      \
      const float* np = asrc((J) + 6);                                       \
      ab[S][0] = ld16(np);                                                   \
      ab[S][1] = ld16(np + 4);                                               \
    }                                                                        \
  }

  FC1_STEP(0,0,10)  FC1_STEP(1,1,10)  FC1_STEP(2,2,10)  FC1_STEP(3,3,10)
  FC1_STEP(4,4,10)  FC1_STEP(5,5,10)  FC1_STEP(6,0,10)  FC1_STEP(7,1,10)
  FC1_STEP(8,2,10)  FC1_STEP(9,3,10)  FC1_STEP(10,4,10) FC1_STEP(11,5,10)
  FC1_STEP(12,0,10) FC1_STEP(13,1,8)  FC1_STEP(14,2,6)  FC1_STEP(15,3,4)
  FC1_STEP(16,4,2)  FC1_STEP(17,5,0)
#undef FC1_STEP
  // vmcnt == 0 here.

  // ---- fc2 prologue: pc0..2 + W0,W1 (11 loads) -- latency hides under handoff ----
  const float* pcp = prev_c + (size_t)rowA * 256 + 4 * lg;
  const short* w2t = wsw + W2T_OFF;
  float4v pcq[3];
  bf16x8  Wq[2][4];
  #pragma unroll
  for (int q = 0; q < 3; ++q) pcq[q] = ld16(pcp + q * 16);
  #pragma unroll
  for (int q = 0; q < 2; ++q) {
    const short* aw = w2t + (q * 16 + ln) * 32 + 8 * lg;
    Wq[q][0] = ld16w(aw);
    Wq[q][1] = ld16w(aw + 256 * 32);
    Wq[q][2] = ld16w(aw + 512 * 32);
    Wq[q][3] = ld16w(aw + 768 * 32);
  }

  // ---- h1 = tanh(.+b1) -> wave-local LDS transpose (biases from LDS) ----
  {
    float4v b1lo = *(const float4v*)&blds[1280 + 4 * lg];
    float4v b1hi = *(const float4v*)&blds[1280 + 16 + 4 * lg];
    uint2 wlo, whi;
    wlo.x = pack2(fast_tanh(acc0[0] + b1lo.x), fast_tanh(acc0[1] + b1lo.y));
    wlo.y = pack2(fast_tanh(acc0[2] + b1lo.z), fast_tanh(acc0[3] + b1lo.w));
    whi.x = pack2(fast_tanh(acc1[0] + b1hi.x), fast_tanh(acc1[1] + b1hi.y));
    whi.y = pack2(fast_tanh(acc1[2] + b1hi.z), fast_tanh(acc1[3] + b1hi.w));
    short* hrow = &h1T[rowL * 40];
    *(uint2*)(hrow + 4 * lg)      = wlo;
    *(uint2*)(hrow + 16 + 4 * lg) = whi;
  }
  asm volatile("s_waitcnt lgkmcnt(0)" ::: "memory");
  __builtin_amdgcn_sched_barrier(0);
  bf16x8 af2 = *(const bf16x8*)(&h1T[rowL * 40] + 8 * lg);

  // ---- fc2: 16 tiles. Wait literals = loads-only counting. ----
  const size_t orow = (size_t)rowA * 256;
  float racc = 0.f;

#define FC2_TILE(T, VM)                                                       \
  {                                                                           \
    asm volatile("s_waitcnt vmcnt(" #VM ")");                                 \
    __builtin_amdgcn_sched_barrier(0);                                        \
    f32x4 gi = {0.f,0.f,0.f,0.f}, gf = {0.f,0.f,0.f,0.f};                     \
    f32x4 gc = {0.f,0.f,0.f,0.f}, go = {0.f,0.f,0.f,0.f};                     \
    gi = __builtin_amdgcn_mfma_f32_16x16x32_bf16(Wq[(T)&1][0], af2, gi,0,0,0);\
    gf = __builtin_amdgcn_mfma_f32_16x16x32_bf16(Wq[(T)&1][1], af2, gf,0,0,0);\
    gc = __builtin_amdgcn_mfma_f32_16x16x32_bf16(Wq[(T)&1][2], af2, gc,0,0,0);\
    go = __builtin_amdgcn_mfma_f32_16x16x32_bf16(Wq[(T)&1][3], af2, go,0,0,0);\
    float4v pcv = pcq[(T) % 3];                                               \
    const int c4 = (T) * 16 + 4 * lg;                                         \
    float4v b2i = *(const float4v*)&blds[c4];                                 \
    float4v b2f = *(const float4v*)&blds[256 + c4];                           \
    float4v b2c = *(const float4v*)&blds[512 + c4];                           \
    float4v b2o = *(const float4v*)&blds[768 + c4];                           \
    float4v wrv = *(const float4v*)&blds[1024 + c4];                          \
    float4v nh, nc2;                                                          \
    _Pragma("unroll")                                                         \
    for (int r = 0; r < 4; ++r) {                                             \
      float iv  = fast_sigmoid(gi[r] + b2i[r]);                               \
      float fv  = fast_sigmoid(gf[r] + b2f[r]);                               \
      float cv  = fast_tanh(gc[r] + b2c[r]);                                  \
      float ov  = fast_sigmoid(go[r] + b2o[r]);                               \
      float ncv = fv * pcv[r] + iv * cv;                                      \
      float nhv = ov * fast_tanh(ncv);                                        \
      nh[r]  = nhv;                                                           \
      nc2[r] = ncv;                                                           \
      racc += nhv * wrv[r];                                                   \
    }                                                                         \
    __builtin_nontemporal_store(nh,  (float4v*)(out_h + orow + c4));          \
    __builtin_nontemporal_store(nc2, (float4v*)(out_c + orow + c4));          \
    if ((T) + 3 <= 15) {  /* never issue a load whose result is dead */       \
      pcq[(T) % 3] = ld16(pcp + ((T) + 3) * 16);                              \
    }                                                                         \
    if ((T) + 2 <= 15) {                                                      \
      const short* awn = w2t + ((((T) + 2) * 16 + ln)) * 32 + 8 * lg;         \
      Wq[(T)&1][0] = ld16w(awn);                                              \
      Wq[(T)&1][1] = ld16w(awn + 256 * 32);                                   \
      Wq[(T)&1][2] = ld16w(awn + 512 * 32);                                   \
      Wq[(T)&1][3] = ld16w(awn + 768 * 32);                                   \
    }                                                                         \
  }

  FC2_TILE(0,4)   FC2_TILE(1,5)   FC2_TILE(2,5)   FC2_TILE(3,5)
  FC2_TILE(4,5)   FC2_TILE(5,5)   FC2_TILE(6,5)   FC2_TILE(7,5)
  FC2_TILE(8,5)   FC2_TILE(9,5)   FC2_TILE(10,5)  FC2_TILE(11,5)
  FC2_TILE(12,5)  FC2_TILE(13,5)  FC2_TILE(14,4)  FC2_TILE(15,0)
#undef FC2_TILE

  // ---- reward: fold lg groups; rdot (acc2[0]) and br never left registers/LDS ----
  racc += __shfl_xor(racc, 16, 64);
  racc += __shfl_xor(racc, 32, 64);
  if (lg == 0) {
    float s = acc2[0] + racc + blds[1312];
    __builtin_nontemporal_store(fast_tanh(s), &out_r[rowA]);
  }
  asm volatile("s_waitcnt vmcnt(0)");
}

extern "C" void kernel_launch(void* const* d_in, const int* in_sizes, int n_in,
                              void* d_out, int out_size, void* d_ws, size_t ws_size,
                              hipStream_t stream) {
  const float* prev_h   = (const float*)d_in[0];
  const float* prev_c   = (const float*)d_in[1];
  const float* action   = (const float*)d_in[2];
  const float* dynamics = (const float*)d_in[3];
  const float* W1 = (const float*)d_in[4];
  const float* b1 = (const float*)d_in[5];
  const float* W2 = (const float*)d_in[6];
  const float* b2 = (const float*)d_in[7];
  const float* Wr = (const float*)d_in[8];
  const float* br = (const float*)d_in[9];

  short* wsw = (short*)d_ws;   // 126,144 bytes used

  float* out_h = (float*)d_out;
  float* out_c = out_h + (size_t)65536 * 256;
  float* out_r = out_c + (size_t)65536 * 256;

  prep_weights<<<242, 256, 0, stream>>>(W1, W2, Wr, b1, b2, br, wsw);
  fclstm_fused<<<512, 512, 0, stream>>>(prev_h, prev_c, action, dynamics,
                                        wsw, out_h, out_c, out_r);
}